// Round 4
// baseline (2083.328 us; speedup 1.0000x reference)
//
#include <hip/hip_runtime.h>

#define CUBE 32

__device__ __forceinline__ float sgpr_f(float v) {
    int i = __builtin_amdgcn_readfirstlane(__float_as_int(v));
    return __int_as_float(i);
}

// ---------------- Kernel A: surface = x @ W_in^T + b_in ----------------
// x [1024][784], W_in [1024][784] -> surface [1024][1024]
__global__ __launch_bounds__(256) void in_gemm(
    const float* __restrict__ x,
    const float* __restrict__ W_in,
    const float* __restrict__ b_in,
    float* __restrict__ surface)
{
    __shared__ __align__(16) float As[16][68];
    __shared__ __align__(16) float Bs[16][68];
    const int t  = threadIdx.x;
    const int tx = t & 15, ty = t >> 4;
    const int bn = blockIdx.x * 64;   // neuron tile
    const int bb = blockIdx.y * 64;   // batch tile

    float acc[4][4];
#pragma unroll
    for (int i = 0; i < 4; ++i)
#pragma unroll
        for (int j = 0; j < 4; ++j) acc[i][j] = 0.0f;

    for (int k0 = 0; k0 < 784; k0 += 16) {
        const int e  = t * 4;
        const int r  = e >> 4;
        const int kk = e & 15;           // 0,4,8,12
        float4 av = *(const float4*)&x[(size_t)(bb + r) * 784 + k0 + kk];
        float4 bv = *(const float4*)&W_in[(size_t)(bn + r) * 784 + k0 + kk];
        As[kk + 0][r] = av.x; As[kk + 1][r] = av.y; As[kk + 2][r] = av.z; As[kk + 3][r] = av.w;
        Bs[kk + 0][r] = bv.x; Bs[kk + 1][r] = bv.y; Bs[kk + 2][r] = bv.z; Bs[kk + 3][r] = bv.w;
        __syncthreads();
#pragma unroll
        for (int kki = 0; kki < 16; ++kki) {
            float4 a = *(const float4*)&As[kki][ty * 4];
            float4 b = *(const float4*)&Bs[kki][tx * 4];
            float aa[4] = {a.x, a.y, a.z, a.w};
            float bbv[4] = {b.x, b.y, b.z, b.w};
#pragma unroll
            for (int i = 0; i < 4; ++i)
#pragma unroll
                for (int j = 0; j < 4; ++j)
                    acc[i][j] = fmaf(aa[i], bbv[j], acc[i][j]);
        }
        __syncthreads();
    }
#pragma unroll
    for (int i = 0; i < 4; ++i) {
        const int row = bb + ty * 4 + i;
#pragma unroll
        for (int j = 0; j < 4; ++j) {
            const int col = bn + tx * 4 + j;
            surface[(size_t)row * 1024 + col] = acc[i][j] + b_in[col];
        }
    }
}

// ---------------- Kernel B: 30-step cube evolution + output GEMM ----------------
// One block per batch; thread (y,x) owns the d-column. ALL per-thread state is
// individually-NAMED scalars (s0..s31, nb0..nb31, cw0..cw26, p0..p9) — r3
// lesson: array forms (even with literal indices) stayed in scratch
// (WRITE_SIZE 835 MB of spill traffic, VGPR=64, kernel scratch-BW-bound).
// Named scalars cannot be demoted to indexed private memory.

#define REP32(M) M(0)M(1)M(2)M(3)M(4)M(5)M(6)M(7)M(8)M(9)M(10)M(11)M(12)M(13)M(14)M(15)M(16)M(17)M(18)M(19)M(20)M(21)M(22)M(23)M(24)M(25)M(26)M(27)M(28)M(29)M(30)M(31)

// Process input plane p (literal); q = p-1 (literal). Contributions:
// aN += plane p * w[kd=0] (feeds output p+1), aC += * w[kd=1] (output p),
// aP += * w[kd=2] (output p-1); then finalize output q = p-1.
#define PLANE(p, q, aN, aC, aP) do {                                           \
    const float v0 = S[p][ty+0][tx+0], v1 = S[p][ty+0][tx+1], v2 = S[p][ty+0][tx+2]; \
    const float v3 = S[p][ty+1][tx+0], v4 = S[p][ty+1][tx+1], v5 = S[p][ty+1][tx+2]; \
    const float v6 = S[p][ty+2][tx+0], v7 = S[p][ty+2][tx+1], v8 = S[p][ty+2][tx+2]; \
    if ((p) < 31) {                                                            \
        aN = fmaf(cw0, v0, aN); aN = fmaf(cw1, v1, aN); aN = fmaf(cw2, v2, aN); \
        aN = fmaf(cw3, v3, aN); aN = fmaf(cw4, v4, aN); aN = fmaf(cw5, v5, aN); \
        aN = fmaf(cw6, v6, aN); aN = fmaf(cw7, v7, aN); aN = fmaf(cw8, v8, aN); \
    }                                                                          \
    aC = fmaf(cw9,  v0, aC); aC = fmaf(cw10, v1, aC); aC = fmaf(cw11, v2, aC); \
    aC = fmaf(cw12, v3, aC); aC = fmaf(cw13, v4, aC); aC = fmaf(cw14, v5, aC); \
    aC = fmaf(cw15, v6, aC); aC = fmaf(cw16, v7, aC); aC = fmaf(cw17, v8, aC); \
    if ((p) >= 1) {                                                            \
        aP = fmaf(cw18, v0, aP); aP = fmaf(cw19, v1, aP); aP = fmaf(cw20, v2, aP); \
        aP = fmaf(cw21, v3, aP); aP = fmaf(cw22, v4, aP); aP = fmaf(cw23, v5, aP); \
        aP = fmaf(cw24, v6, aP); aP = fmaf(cw25, v7, aP); aP = fmaf(cw26, v8, aP); \
        const float pre = aP + nb##q;                                          \
        const float tE  = __builtin_amdgcn_exp2f(pre * 2.8853900817779268f);   \
        const float h   = 1.0f - 2.0f * __builtin_amdgcn_rcpf(tE + 1.0f);      \
        s##q = 0.5f * (s##q + h);                                              \
        aP = 0.0f;                                                             \
    }                                                                          \
} while (0);

__global__ __launch_bounds__(1024, 4) __attribute__((amdgpu_waves_per_eu(4, 4)))
void cube_evolve(
    const float* __restrict__ surface,   // [1024][1024]
    const float* __restrict__ conv_w,    // [27]  (kd,ky,kx)
    const float* __restrict__ nbias,     // [32768] (d,y,x)
    const float* __restrict__ W_out,     // [10][32768]
    const float* __restrict__ b_out,     // [10]
    const int*   __restrict__ steps_p,   // [1]
    float* __restrict__ out)             // [1024][10]
{
    __shared__ float S[32][34][34];      // 147,968 B -> 1 block/CU, 4 waves/EU
    __shared__ float red[10][16];

    const int b   = blockIdx.x;
    const int tx  = threadIdx.x;         // x
    const int ty  = threadIdx.y;         // y
    const int tid = ty * 32 + tx;
    const int steps = steps_p[0];

    // zero entire LDS cube (borders must be 0, and they stay 0)
    for (int i = tid; i < 32 * 34 * 34; i += 1024) ((float*)S)[i] = 0.0f;

    // conv weights -> named uniform scalars (SGPRs)
    const float cw0  = sgpr_f(conv_w[0]),  cw1  = sgpr_f(conv_w[1]),  cw2  = sgpr_f(conv_w[2]);
    const float cw3  = sgpr_f(conv_w[3]),  cw4  = sgpr_f(conv_w[4]),  cw5  = sgpr_f(conv_w[5]);
    const float cw6  = sgpr_f(conv_w[6]),  cw7  = sgpr_f(conv_w[7]),  cw8  = sgpr_f(conv_w[8]);
    const float cw9  = sgpr_f(conv_w[9]),  cw10 = sgpr_f(conv_w[10]), cw11 = sgpr_f(conv_w[11]);
    const float cw12 = sgpr_f(conv_w[12]), cw13 = sgpr_f(conv_w[13]), cw14 = sgpr_f(conv_w[14]);
    const float cw15 = sgpr_f(conv_w[15]), cw16 = sgpr_f(conv_w[16]), cw17 = sgpr_f(conv_w[17]);
    const float cw18 = sgpr_f(conv_w[18]), cw19 = sgpr_f(conv_w[19]), cw20 = sgpr_f(conv_w[20]);
    const float cw21 = sgpr_f(conv_w[21]), cw22 = sgpr_f(conv_w[22]), cw23 = sgpr_f(conv_w[23]);
    const float cw24 = sgpr_f(conv_w[24]), cw25 = sgpr_f(conv_w[25]), cw26 = sgpr_f(conv_w[26]);

    // per-thread state + injection columns: named scalars only
#define DECL_SD(d) float s##d = 0.0f;
    REP32(DECL_SD)
#define DECL_NB(d) float nb##d = nbias[(d) * 1024 + tid];
    REP32(DECL_NB)
    nb0 += surface[(size_t)b * 1024 + tid];

    __syncthreads();

    for (int st = 0; st < steps; ++st) {
        // publish old state
#define PUB(d) S[d][ty + 1][tx + 1] = s##d;
        REP32(PUB)
        __syncthreads();

        float acc0 = 0.0f, acc1 = 0.0f, acc2 = 0.0f;
        // rotation: plane p uses (aN, aC, aP) = (acc[(p+1)%3], acc[p%3], acc[(p+2)%3])
        PLANE( 0,  0, acc1, acc0, acc2)
        PLANE( 1,  0, acc2, acc1, acc0)
        PLANE( 2,  1, acc0, acc2, acc1)
        PLANE( 3,  2, acc1, acc0, acc2)
        PLANE( 4,  3, acc2, acc1, acc0)
        PLANE( 5,  4, acc0, acc2, acc1)
        PLANE( 6,  5, acc1, acc0, acc2)
        PLANE( 7,  6, acc2, acc1, acc0)
        PLANE( 8,  7, acc0, acc2, acc1)
        PLANE( 9,  8, acc1, acc0, acc2)
        PLANE(10,  9, acc2, acc1, acc0)
        PLANE(11, 10, acc0, acc2, acc1)
        PLANE(12, 11, acc1, acc0, acc2)
        PLANE(13, 12, acc2, acc1, acc0)
        PLANE(14, 13, acc0, acc2, acc1)
        PLANE(15, 14, acc1, acc0, acc2)
        PLANE(16, 15, acc2, acc1, acc0)
        PLANE(17, 16, acc0, acc2, acc1)
        PLANE(18, 17, acc1, acc0, acc2)
        PLANE(19, 18, acc2, acc1, acc0)
        PLANE(20, 19, acc0, acc2, acc1)
        PLANE(21, 20, acc1, acc0, acc2)
        PLANE(22, 21, acc2, acc1, acc0)
        PLANE(23, 22, acc0, acc2, acc1)
        PLANE(24, 23, acc1, acc0, acc2)
        PLANE(25, 24, acc2, acc1, acc0)
        PLANE(26, 25, acc0, acc2, acc1)
        PLANE(27, 26, acc1, acc0, acc2)
        PLANE(28, 27, acc2, acc1, acc0)
        PLANE(29, 28, acc0, acc2, acc1)
        PLANE(30, 29, acc1, acc0, acc2)
        PLANE(31, 30, acc2, acc1, acc0)
        { // finalize output plane 31 (contributions: plane 30 kd=0 + plane 31 kd=1 -> acc1)
            const float pre = acc1 + nb31;
            const float tE  = __builtin_amdgcn_exp2f(pre * 2.8853900817779268f);
            const float h   = 1.0f - 2.0f * __builtin_amdgcn_rcpf(tE + 1.0f);
            s31 = 0.5f * (s31 + h);
        }
        __syncthreads();
    }

    // ---- fused output GEMM: out[b][o] = sum_d s_d * W_out[o][d*1024+tid] + b_out[o]
    float p0 = 0.f, p1 = 0.f, p2 = 0.f, p3 = 0.f, p4 = 0.f;
    float p5 = 0.f, p6 = 0.f, p7 = 0.f, p8 = 0.f, p9 = 0.f;
#define OUTD(d) {                                                              \
    const float* wp = &W_out[(size_t)(d) * 1024 + tid];                        \
    p0 = fmaf(s##d, wp[0 * 32768], p0);  p1 = fmaf(s##d, wp[1 * 32768], p1);   \
    p2 = fmaf(s##d, wp[2 * 32768], p2);  p3 = fmaf(s##d, wp[3 * 32768], p3);   \
    p4 = fmaf(s##d, wp[4 * 32768], p4);  p5 = fmaf(s##d, wp[5 * 32768], p5);   \
    p6 = fmaf(s##d, wp[6 * 32768], p6);  p7 = fmaf(s##d, wp[7 * 32768], p7);   \
    p8 = fmaf(s##d, wp[8 * 32768], p8);  p9 = fmaf(s##d, wp[9 * 32768], p9); }
    REP32(OUTD)

    const int lane = tid & 63, wid = tid >> 6;
#define RED(o, pv) {                                                           \
    float vv = pv;                                                             \
    vv += __shfl_down(vv, 32, 64); vv += __shfl_down(vv, 16, 64);              \
    vv += __shfl_down(vv, 8, 64);  vv += __shfl_down(vv, 4, 64);               \
    vv += __shfl_down(vv, 2, 64);  vv += __shfl_down(vv, 1, 64);               \
    if (lane == 0) red[o][wid] = vv; }
    RED(0, p0) RED(1, p1) RED(2, p2) RED(3, p3) RED(4, p4)
    RED(5, p5) RED(6, p6) RED(7, p7) RED(8, p8) RED(9, p9)
    __syncthreads();
    if (tid < 10) {
        float sum = b_out[tid];
#pragma unroll
        for (int wdx = 0; wdx < 16; ++wdx) sum += red[tid][wdx];
        out[(size_t)b * 10 + tid] = sum;
    }
}

// ---------------- launcher ----------------
extern "C" void kernel_launch(void* const* d_in, const int* in_sizes, int n_in,
                              void* d_out, int out_size, void* d_ws, size_t ws_size,
                              hipStream_t stream) {
    const float* x      = (const float*)d_in[0];
    const float* W_in   = (const float*)d_in[1];
    const float* b_in   = (const float*)d_in[2];
    const float* conv_w = (const float*)d_in[3];
    const float* nbias  = (const float*)d_in[4];
    const float* W_out  = (const float*)d_in[5];
    const float* b_out  = (const float*)d_in[6];
    const int*   steps  = (const int*)d_in[7];
    float* out = (float*)d_out;
    float* surface = (float*)d_ws;   // 1024*1024 f32 = 4 MB scratch

    in_gemm<<<dim3(16, 16), 256, 0, stream>>>(x, W_in, b_in, surface);
    cube_evolve<<<1024, dim3(32, 32), 0, stream>>>(surface, conv_w, nbias,
                                                   W_out, b_out, steps, out);
}

// Round 5
// 1826.470 us; speedup vs baseline: 1.1406x; 1.1406x over previous
//
#include <hip/hip_runtime.h>

#define CUBE 32

__device__ __forceinline__ float sgpr_f(float v) {
    int i = __builtin_amdgcn_readfirstlane(__float_as_int(v));
    return __int_as_float(i);
}

// ---------------- Kernel A: surface = x @ W_in^T + b_in ----------------
// x [1024][784], W_in [1024][784] -> surface [1024][1024]
__global__ __launch_bounds__(256) void in_gemm(
    const float* __restrict__ x,
    const float* __restrict__ W_in,
    const float* __restrict__ b_in,
    float* __restrict__ surface)
{
    __shared__ __align__(16) float As[16][68];
    __shared__ __align__(16) float Bs[16][68];
    const int t  = threadIdx.x;
    const int tx = t & 15, ty = t >> 4;
    const int bn = blockIdx.x * 64;   // neuron tile
    const int bb = blockIdx.y * 64;   // batch tile

    float acc[4][4];
#pragma unroll
    for (int i = 0; i < 4; ++i)
#pragma unroll
        for (int j = 0; j < 4; ++j) acc[i][j] = 0.0f;

    for (int k0 = 0; k0 < 784; k0 += 16) {
        const int e  = t * 4;
        const int r  = e >> 4;
        const int kk = e & 15;           // 0,4,8,12
        float4 av = *(const float4*)&x[(size_t)(bb + r) * 784 + k0 + kk];
        float4 bv = *(const float4*)&W_in[(size_t)(bn + r) * 784 + k0 + kk];
        As[kk + 0][r] = av.x; As[kk + 1][r] = av.y; As[kk + 2][r] = av.z; As[kk + 3][r] = av.w;
        Bs[kk + 0][r] = bv.x; Bs[kk + 1][r] = bv.y; Bs[kk + 2][r] = bv.z; Bs[kk + 3][r] = bv.w;
        __syncthreads();
#pragma unroll
        for (int kki = 0; kki < 16; ++kki) {
            float4 a = *(const float4*)&As[kki][ty * 4];
            float4 b = *(const float4*)&Bs[kki][tx * 4];
            float aa[4] = {a.x, a.y, a.z, a.w};
            float bbv[4] = {b.x, b.y, b.z, b.w};
#pragma unroll
            for (int i = 0; i < 4; ++i)
#pragma unroll
                for (int j = 0; j < 4; ++j)
                    acc[i][j] = fmaf(aa[i], bbv[j], acc[i][j]);
        }
        __syncthreads();
    }
#pragma unroll
    for (int i = 0; i < 4; ++i) {
        const int row = bb + ty * 4 + i;
#pragma unroll
        for (int j = 0; j < 4; ++j) {
            const int col = bn + tx * 4 + j;
            surface[(size_t)row * 1024 + col] = acc[i][j] + b_in[col];
        }
    }
}

// ---------------- Kernel B: 30-step cube evolution + output GEMM ----------------
// One block per batch; thread (y,x) owns the d-column (s0..s31 named scalars).
// r4 lesson: the register allocator caps this kernel at 64 VGPRs regardless of
// launch_bounds/waves_per_eu, spilling anything beyond (900 MB HBM scratch
// traffic). Fix: FIT in 64 VGPRs — drop the 32 nb registers; nbias is a
// 128 KB broadcast array (same for all blocks, L2-resident), so re-load each
// value just-in-time, software-pipelined 3 planes ahead of its use.
// Live set: s(32) + window(9) + acc(3) + nb in flight(~3) + addr(~5) ~= 52.

#define REP32(M) M(0)M(1)M(2)M(3)M(4)M(5)M(6)M(7)M(8)M(9)M(10)M(11)M(12)M(13)M(14)M(15)M(16)M(17)M(18)M(19)M(20)M(21)M(22)M(23)M(24)M(25)M(26)M(27)M(28)M(29)M(30)M(31)

// Process input plane p (literal); q = p-1 (literal, finalize target);
// r = p+2 (literal, nb prefetch target, dead for p>=30).
#define PLANE(p, q, r, aN, aC, aP) do {                                        \
    if ((p) <= 29) { nb_f_##r = nbp[(r) * 1024]; }                             \
    const float v0 = S[p][ty+0][tx+0], v1 = S[p][ty+0][tx+1], v2 = S[p][ty+0][tx+2]; \
    const float v3 = S[p][ty+1][tx+0], v4 = S[p][ty+1][tx+1], v5 = S[p][ty+1][tx+2]; \
    const float v6 = S[p][ty+2][tx+0], v7 = S[p][ty+2][tx+1], v8 = S[p][ty+2][tx+2]; \
    if ((p) < 31) {                                                            \
        aN = fmaf(cw0, v0, aN); aN = fmaf(cw1, v1, aN); aN = fmaf(cw2, v2, aN); \
        aN = fmaf(cw3, v3, aN); aN = fmaf(cw4, v4, aN); aN = fmaf(cw5, v5, aN); \
        aN = fmaf(cw6, v6, aN); aN = fmaf(cw7, v7, aN); aN = fmaf(cw8, v8, aN); \
    }                                                                          \
    aC = fmaf(cw9,  v0, aC); aC = fmaf(cw10, v1, aC); aC = fmaf(cw11, v2, aC); \
    aC = fmaf(cw12, v3, aC); aC = fmaf(cw13, v4, aC); aC = fmaf(cw14, v5, aC); \
    aC = fmaf(cw15, v6, aC); aC = fmaf(cw16, v7, aC); aC = fmaf(cw17, v8, aC); \
    if ((p) >= 1) {                                                            \
        aP = fmaf(cw18, v0, aP); aP = fmaf(cw19, v1, aP); aP = fmaf(cw20, v2, aP); \
        aP = fmaf(cw21, v3, aP); aP = fmaf(cw22, v4, aP); aP = fmaf(cw23, v5, aP); \
        aP = fmaf(cw24, v6, aP); aP = fmaf(cw25, v7, aP); aP = fmaf(cw26, v8, aP); \
        const float pre = aP + nb_f_##q + (((q) == 0) ? surf : 0.0f);          \
        const float tE  = __builtin_amdgcn_exp2f(pre * 2.8853900817779268f);   \
        const float h   = 1.0f - 2.0f * __builtin_amdgcn_rcpf(tE + 1.0f);      \
        s##q = 0.5f * (s##q + h);                                              \
        aP = 0.0f;                                                             \
    }                                                                          \
} while (0);

__global__ __launch_bounds__(1024) void cube_evolve(
    const float* __restrict__ surface,   // [1024][1024]
    const float* __restrict__ conv_w,    // [27]  (kd,ky,kx)
    const float* __restrict__ nbias,     // [32768] (d,y,x)
    const float* __restrict__ W_out,     // [10][32768]
    const float* __restrict__ b_out,     // [10]
    const int*   __restrict__ steps_p,   // [1]
    float* __restrict__ out)             // [1024][10]
{
    __shared__ float S[32][34][34];      // 147,968 B -> 1 block/CU, 4 waves/EU
    __shared__ float red[10][16];

    const int b   = blockIdx.x;
    const int tx  = threadIdx.x;         // x
    const int ty  = threadIdx.y;         // y
    const int tid = ty * 32 + tx;
    const int steps = steps_p[0];

    // zero entire LDS cube (borders must be 0, and they stay 0)
    for (int i = tid; i < 32 * 34 * 34; i += 1024) ((float*)S)[i] = 0.0f;

    // conv weights -> named uniform scalars (SGPRs)
    const float cw0  = sgpr_f(conv_w[0]),  cw1  = sgpr_f(conv_w[1]),  cw2  = sgpr_f(conv_w[2]);
    const float cw3  = sgpr_f(conv_w[3]),  cw4  = sgpr_f(conv_w[4]),  cw5  = sgpr_f(conv_w[5]);
    const float cw6  = sgpr_f(conv_w[6]),  cw7  = sgpr_f(conv_w[7]),  cw8  = sgpr_f(conv_w[8]);
    const float cw9  = sgpr_f(conv_w[9]),  cw10 = sgpr_f(conv_w[10]), cw11 = sgpr_f(conv_w[11]);
    const float cw12 = sgpr_f(conv_w[12]), cw13 = sgpr_f(conv_w[13]), cw14 = sgpr_f(conv_w[14]);
    const float cw15 = sgpr_f(conv_w[15]), cw16 = sgpr_f(conv_w[16]), cw17 = sgpr_f(conv_w[17]);
    const float cw18 = sgpr_f(conv_w[18]), cw19 = sgpr_f(conv_w[19]), cw20 = sgpr_f(conv_w[20]);
    const float cw21 = sgpr_f(conv_w[21]), cw22 = sgpr_f(conv_w[22]), cw23 = sgpr_f(conv_w[23]);
    const float cw24 = sgpr_f(conv_w[24]), cw25 = sgpr_f(conv_w[25]), cw26 = sgpr_f(conv_w[26]);

    // per-thread pointers
    const float* nbp = nbias + tid;          // nb for plane d at nbp[d*1024]
    const float  surf = surface[(size_t)b * 1024 + tid];

    // per-thread state: named scalars only (32 persistent VGPRs)
#define DECL_SD(d) float s##d = 0.0f;
    REP32(DECL_SD)

    __syncthreads();

    for (int st = 0; st < steps; ++st) {
        // nb values arrive via pipelined L2 loads; declare slots (SSA, ~3 live)
#define DECL_NBF(d) float nb_f_##d;
        REP32(DECL_NBF)
        // prologue prefetch: needed at planes 1 and 2 (finalize of q=0,1)
        nb_f_0 = nbp[0];
        nb_f_1 = nbp[1024];

        // publish old state
#define PUB(d) S[d][ty + 1][tx + 1] = s##d;
        REP32(PUB)
        __syncthreads();

        float acc0 = 0.0f, acc1 = 0.0f, acc2 = 0.0f;
        // rotation: plane p uses (aN, aC, aP) = (acc[(p+1)%3], acc[p%3], acc[(p+2)%3])
        PLANE( 0,  0,  2, acc1, acc0, acc2)
        PLANE( 1,  0,  3, acc2, acc1, acc0)
        PLANE( 2,  1,  4, acc0, acc2, acc1)
        PLANE( 3,  2,  5, acc1, acc0, acc2)
        PLANE( 4,  3,  6, acc2, acc1, acc0)
        PLANE( 5,  4,  7, acc0, acc2, acc1)
        PLANE( 6,  5,  8, acc1, acc0, acc2)
        PLANE( 7,  6,  9, acc2, acc1, acc0)
        PLANE( 8,  7, 10, acc0, acc2, acc1)
        PLANE( 9,  8, 11, acc1, acc0, acc2)
        PLANE(10,  9, 12, acc2, acc1, acc0)
        PLANE(11, 10, 13, acc0, acc2, acc1)
        PLANE(12, 11, 14, acc1, acc0, acc2)
        PLANE(13, 12, 15, acc2, acc1, acc0)
        PLANE(14, 13, 16, acc0, acc2, acc1)
        PLANE(15, 14, 17, acc1, acc0, acc2)
        PLANE(16, 15, 18, acc2, acc1, acc0)
        PLANE(17, 16, 19, acc0, acc2, acc1)
        PLANE(18, 17, 20, acc1, acc0, acc2)
        PLANE(19, 18, 21, acc2, acc1, acc0)
        PLANE(20, 19, 22, acc0, acc2, acc1)
        PLANE(21, 20, 23, acc1, acc0, acc2)
        PLANE(22, 21, 24, acc2, acc1, acc0)
        PLANE(23, 22, 25, acc0, acc2, acc1)
        PLANE(24, 23, 26, acc1, acc0, acc2)
        PLANE(25, 24, 27, acc2, acc1, acc0)
        PLANE(26, 25, 28, acc0, acc2, acc1)
        PLANE(27, 26, 29, acc1, acc0, acc2)
        PLANE(28, 27, 30, acc2, acc1, acc0)
        PLANE(29, 28, 31, acc0, acc2, acc1)
        PLANE(30, 29, 31, acc1, acc0, acc2)
        PLANE(31, 30, 31, acc2, acc1, acc0)
        { // finalize output plane 31 (plane 30 kd=0 + plane 31 kd=1 -> acc1)
            const float pre = acc1 + nb_f_31;
            const float tE  = __builtin_amdgcn_exp2f(pre * 2.8853900817779268f);
            const float h   = 1.0f - 2.0f * __builtin_amdgcn_rcpf(tE + 1.0f);
            s31 = 0.5f * (s31 + h);
        }
        __syncthreads();
    }

    // ---- fused output GEMM: out[b][o] = sum_d s_d * W_out[o][d*1024+tid] + b_out[o]
    float p0 = 0.f, p1 = 0.f, p2 = 0.f, p3 = 0.f, p4 = 0.f;
    float p5 = 0.f, p6 = 0.f, p7 = 0.f, p8 = 0.f, p9 = 0.f;
#define OUTD(d) {                                                              \
    const float* wp = &W_out[(size_t)(d) * 1024 + tid];                        \
    p0 = fmaf(s##d, wp[0 * 32768], p0);  p1 = fmaf(s##d, wp[1 * 32768], p1);   \
    p2 = fmaf(s##d, wp[2 * 32768], p2);  p3 = fmaf(s##d, wp[3 * 32768], p3);   \
    p4 = fmaf(s##d, wp[4 * 32768], p4);  p5 = fmaf(s##d, wp[5 * 32768], p5);   \
    p6 = fmaf(s##d, wp[6 * 32768], p6);  p7 = fmaf(s##d, wp[7 * 32768], p7);   \
    p8 = fmaf(s##d, wp[8 * 32768], p8);  p9 = fmaf(s##d, wp[9 * 32768], p9); }
    REP32(OUTD)

    const int lane = tid & 63, wid = tid >> 6;
#define RED(o, pv) {                                                           \
    float vv = pv;                                                             \
    vv += __shfl_down(vv, 32, 64); vv += __shfl_down(vv, 16, 64);              \
    vv += __shfl_down(vv, 8, 64);  vv += __shfl_down(vv, 4, 64);               \
    vv += __shfl_down(vv, 2, 64);  vv += __shfl_down(vv, 1, 64);               \
    if (lane == 0) red[o][wid] = vv; }
    RED(0, p0) RED(1, p1) RED(2, p2) RED(3, p3) RED(4, p4)
    RED(5, p5) RED(6, p6) RED(7, p7) RED(8, p8) RED(9, p9)
    __syncthreads();
    if (tid < 10) {
        float sum = b_out[tid];
#pragma unroll
        for (int wdx = 0; wdx < 16; ++wdx) sum += red[tid][wdx];
        out[(size_t)b * 10 + tid] = sum;
    }
}

// ---------------- launcher ----------------
extern "C" void kernel_launch(void* const* d_in, const int* in_sizes, int n_in,
                              void* d_out, int out_size, void* d_ws, size_t ws_size,
                              hipStream_t stream) {
    const float* x      = (const float*)d_in[0];
    const float* W_in   = (const float*)d_in[1];
    const float* b_in   = (const float*)d_in[2];
    const float* conv_w = (const float*)d_in[3];
    const float* nbias  = (const float*)d_in[4];
    const float* W_out  = (const float*)d_in[5];
    const float* b_out  = (const float*)d_in[6];
    const int*   steps  = (const int*)d_in[7];
    float* out = (float*)d_out;
    float* surface = (float*)d_ws;   // 1024*1024 f32 = 4 MB scratch

    in_gemm<<<dim3(16, 16), 256, 0, stream>>>(x, W_in, b_in, surface);
    cube_evolve<<<1024, dim3(32, 32), 0, stream>>>(surface, conv_w, nbias,
                                                   W_out, b_out, steps, out);
}

// Round 7
// 1380.026 us; speedup vs baseline: 1.5096x; 1.3235x over previous
//
#include <hip/hip_runtime.h>

#define CUBE 32

__device__ __forceinline__ float sgpr_f(float v) {
    int i = __builtin_amdgcn_readfirstlane(__float_as_int(v));
    return __int_as_float(i);
}

// ---------------- Kernel A: surface = x @ W_in^T + b_in ----------------
__global__ __launch_bounds__(256) void in_gemm(
    const float* __restrict__ x,
    const float* __restrict__ W_in,
    const float* __restrict__ b_in,
    float* __restrict__ surface)
{
    __shared__ __align__(16) float As[16][68];
    __shared__ __align__(16) float Bs[16][68];
    const int t  = threadIdx.x;
    const int tx = t & 15, ty = t >> 4;
    const int bn = blockIdx.x * 64;
    const int bb = blockIdx.y * 64;

    float acc[4][4];
#pragma unroll
    for (int i = 0; i < 4; ++i)
#pragma unroll
        for (int j = 0; j < 4; ++j) acc[i][j] = 0.0f;

    for (int k0 = 0; k0 < 784; k0 += 16) {
        const int e  = t * 4;
        const int r  = e >> 4;
        const int kk = e & 15;
        float4 av = *(const float4*)&x[(size_t)(bb + r) * 784 + k0 + kk];
        float4 bv = *(const float4*)&W_in[(size_t)(bn + r) * 784 + k0 + kk];
        As[kk + 0][r] = av.x; As[kk + 1][r] = av.y; As[kk + 2][r] = av.z; As[kk + 3][r] = av.w;
        Bs[kk + 0][r] = bv.x; Bs[kk + 1][r] = bv.y; Bs[kk + 2][r] = bv.z; Bs[kk + 3][r] = bv.w;
        __syncthreads();
#pragma unroll
        for (int kki = 0; kki < 16; ++kki) {
            float4 a = *(const float4*)&As[kki][ty * 4];
            float4 b = *(const float4*)&Bs[kki][tx * 4];
            float aa[4] = {a.x, a.y, a.z, a.w};
            float bbv[4] = {b.x, b.y, b.z, b.w};
#pragma unroll
            for (int i = 0; i < 4; ++i)
#pragma unroll
                for (int j = 0; j < 4; ++j)
                    acc[i][j] = fmaf(aa[i], bbv[j], acc[i][j]);
        }
        __syncthreads();
    }
#pragma unroll
    for (int i = 0; i < 4; ++i) {
        const int row = bb + ty * 4 + i;
#pragma unroll
        for (int j = 0; j < 4; ++j) {
            const int col = bn + tx * 4 + j;
            surface[(size_t)row * 1024 + col] = acc[i][j] + b_in[col];
        }
    }
}

// ---------------- Kernel B: state-in-LDS cube evolution + output GEMM ----------
// 512 threads (16 xg × 32 y), 8 waves. Thread owns x = {2tx, 2tx+1} of row y.
// State ONLY in LDS S[32][34][34]: y'=y+1 (halo rows 0,33 = 0), x'=x+1 (halo
// cols 0,33 = 0). Per plane p: barrier; 6× ds_read_b64 covering the 3×4 input
// window (x-halos come FROM LDS halo columns — r6 lesson: the DPP lane-shift
// halo exchange produced boundary-column errors; removed entirely); accumulate
// into 3 rotating output slots; finalize output q=p-1 (tanh+blend) and write
// it IN-PLACE to S[q] (phase p reads only plane p, writes only plane p-1;
// every same-plane write/read pair is barrier-separated). No per-thread
// arrays -> the 64-VGPR allocator cap (r2-r5: 900 MB scratch traffic) is
// harmless: live set ~25 scalars.

#define REP32(M) M(0)M(1)M(2)M(3)M(4)M(5)M(6)M(7)M(8)M(9)M(10)M(11)M(12)M(13)M(14)M(15)M(16)M(17)M(18)M(19)M(20)M(21)M(22)M(23)M(24)M(25)M(26)M(27)M(28)M(29)M(30)M(31)

// aN feeds output p+1 (kd=0, cw0-8), aC output p (kd=1, cw9-17),
// aP output p-1 (kd=2, cw18-26). Finalize output q=p-1.
// out0 at x=2tx: (l,c,r) = (a.x, a.y, b.x); out1 at x=2tx+1: (a.y, b.x, b.y).
#define PLANE(p, q, aN0, aN1, aC0, aC1, aP0, aP1) {                            \
    __syncthreads();                                                           \
    nb_##p = *(const float2*)&nbias[(p) * 1024 + nboff];                       \
    const float2 a0 = *(const float2*)&S[p][ty + 0][tx2];                      \
    const float2 b0 = *(const float2*)&S[p][ty + 0][tx2 + 2];                  \
    const float2 a1 = *(const float2*)&S[p][ty + 1][tx2];                      \
    const float2 b1 = *(const float2*)&S[p][ty + 1][tx2 + 2];                  \
    const float2 a2 = *(const float2*)&S[p][ty + 2][tx2];                      \
    const float2 b2 = *(const float2*)&S[p][ty + 2][tx2 + 2];                  \
    if ((p) < 31) {                                                            \
        aN0 = fmaf(cw0, a0.x, aN0); aN0 = fmaf(cw1, a0.y, aN0); aN0 = fmaf(cw2, b0.x, aN0); \
        aN0 = fmaf(cw3, a1.x, aN0); aN0 = fmaf(cw4, a1.y, aN0); aN0 = fmaf(cw5, b1.x, aN0); \
        aN0 = fmaf(cw6, a2.x, aN0); aN0 = fmaf(cw7, a2.y, aN0); aN0 = fmaf(cw8, b2.x, aN0); \
        aN1 = fmaf(cw0, a0.y, aN1); aN1 = fmaf(cw1, b0.x, aN1); aN1 = fmaf(cw2, b0.y, aN1); \
        aN1 = fmaf(cw3, a1.y, aN1); aN1 = fmaf(cw4, b1.x, aN1); aN1 = fmaf(cw5, b1.y, aN1); \
        aN1 = fmaf(cw6, a2.y, aN1); aN1 = fmaf(cw7, b2.x, aN1); aN1 = fmaf(cw8, b2.y, aN1); \
    }                                                                          \
    aC0 = fmaf(cw9,  a0.x, aC0); aC0 = fmaf(cw10, a0.y, aC0); aC0 = fmaf(cw11, b0.x, aC0); \
    aC0 = fmaf(cw12, a1.x, aC0); aC0 = fmaf(cw13, a1.y, aC0); aC0 = fmaf(cw14, b1.x, aC0); \
    aC0 = fmaf(cw15, a2.x, aC0); aC0 = fmaf(cw16, a2.y, aC0); aC0 = fmaf(cw17, b2.x, aC0); \
    aC1 = fmaf(cw9,  a0.y, aC1); aC1 = fmaf(cw10, b0.x, aC1); aC1 = fmaf(cw11, b0.y, aC1); \
    aC1 = fmaf(cw12, a1.y, aC1); aC1 = fmaf(cw13, b1.x, aC1); aC1 = fmaf(cw14, b1.y, aC1); \
    aC1 = fmaf(cw15, a2.y, aC1); aC1 = fmaf(cw16, b2.x, aC1); aC1 = fmaf(cw17, b2.y, aC1); \
    if ((p) >= 1) {                                                            \
        aP0 = fmaf(cw18, a0.x, aP0); aP0 = fmaf(cw19, a0.y, aP0); aP0 = fmaf(cw20, b0.x, aP0); \
        aP0 = fmaf(cw21, a1.x, aP0); aP0 = fmaf(cw22, a1.y, aP0); aP0 = fmaf(cw23, b1.x, aP0); \
        aP0 = fmaf(cw24, a2.x, aP0); aP0 = fmaf(cw25, a2.y, aP0); aP0 = fmaf(cw26, b2.x, aP0); \
        aP1 = fmaf(cw18, a0.y, aP1); aP1 = fmaf(cw19, b0.x, aP1); aP1 = fmaf(cw20, b0.y, aP1); \
        aP1 = fmaf(cw21, a1.y, aP1); aP1 = fmaf(cw22, b1.x, aP1); aP1 = fmaf(cw23, b1.y, aP1); \
        aP1 = fmaf(cw24, a2.y, aP1); aP1 = fmaf(cw25, b2.x, aP1); aP1 = fmaf(cw26, b2.y, aP1); \
        const float pre0 = aP0 + nb_##q.x + (((q) == 0) ? sf0 : 0.0f);         \
        const float pre1 = aP1 + nb_##q.y + (((q) == 0) ? sf1 : 0.0f);         \
        const float h0 = 1.0f - 2.0f * __builtin_amdgcn_rcpf(                  \
            __builtin_amdgcn_exp2f(pre0 * 2.8853900817779268f) + 1.0f);        \
        const float h1 = 1.0f - 2.0f * __builtin_amdgcn_rcpf(                  \
            __builtin_amdgcn_exp2f(pre1 * 2.8853900817779268f) + 1.0f);        \
        S[q][ty + 1][tx2 + 1] = 0.5f * (c0 + h0);                              \
        S[q][ty + 1][tx2 + 2] = 0.5f * (c1 + h1);                              \
        aP0 = 0.0f; aP1 = 0.0f;                                                \
    }                                                                          \
    c0 = a1.y; c1 = b1.x;                                                      \
}

__global__ __launch_bounds__(512) void cube_evolve(
    const float* __restrict__ surface,   // [1024][1024]
    const float* __restrict__ conv_w,    // [27]  (kd,ky,kx)
    const float* __restrict__ nbias,     // [32768] (d,y,x)
    const float* __restrict__ W_out,     // [10][32768]
    const float* __restrict__ b_out,     // [10]
    const int*   __restrict__ steps_p,   // [1]
    float* __restrict__ out)             // [1024][10]
{
    __shared__ float S[32][34][34];      // 147,968 B; halo rows/cols stay 0
    __shared__ float red[10][8];

    const int b   = blockIdx.x;
    const int tx  = threadIdx.x;         // xg: 0..15, owns x = 2tx, 2tx+1
    const int ty  = threadIdx.y;         // y:  0..31
    const int tid = ty * 16 + tx;
    const int tx2 = tx * 2;              // x' base of the 4-wide read window
    const int nboff = ty * 32 + tx2;
    const int steps = steps_p[0];

    // zero state + halos
    for (int i = tid; i < 32 * 34 * 34; i += 512) ((float*)S)[i] = 0.0f;

    // conv weights -> uniform scalars (SGPRs)
    const float cw0  = sgpr_f(conv_w[0]),  cw1  = sgpr_f(conv_w[1]),  cw2  = sgpr_f(conv_w[2]);
    const float cw3  = sgpr_f(conv_w[3]),  cw4  = sgpr_f(conv_w[4]),  cw5  = sgpr_f(conv_w[5]);
    const float cw6  = sgpr_f(conv_w[6]),  cw7  = sgpr_f(conv_w[7]),  cw8  = sgpr_f(conv_w[8]);
    const float cw9  = sgpr_f(conv_w[9]),  cw10 = sgpr_f(conv_w[10]), cw11 = sgpr_f(conv_w[11]);
    const float cw12 = sgpr_f(conv_w[12]), cw13 = sgpr_f(conv_w[13]), cw14 = sgpr_f(conv_w[14]);
    const float cw15 = sgpr_f(conv_w[15]), cw16 = sgpr_f(conv_w[16]), cw17 = sgpr_f(conv_w[17]);
    const float cw18 = sgpr_f(conv_w[18]), cw19 = sgpr_f(conv_w[19]), cw20 = sgpr_f(conv_w[20]);
    const float cw21 = sgpr_f(conv_w[21]), cw22 = sgpr_f(conv_w[22]), cw23 = sgpr_f(conv_w[23]);
    const float cw24 = sgpr_f(conv_w[24]), cw25 = sgpr_f(conv_w[25]), cw26 = sgpr_f(conv_w[26]);

    const float2 sfv = *(const float2*)&surface[(size_t)b * 1024 + nboff];
    const float sf0 = sfv.x, sf1 = sfv.y;

    for (int st = 0; st < steps; ++st) {
#define DECL_NB(d) float2 nb_##d;
        REP32(DECL_NB)
        float aX0 = 0.f, aX1 = 0.f, aY0 = 0.f, aY1 = 0.f, aZ0 = 0.f, aZ1 = 0.f;
        float c0 = 0.f, c1 = 0.f;
        // slot rotation (period 3): p%3==0 -> (Y,X,Z); 1 -> (Z,Y,X); 2 -> (X,Z,Y)
        PLANE( 0,  0, aY0, aY1, aX0, aX1, aZ0, aZ1)
        PLANE( 1,  0, aZ0, aZ1, aY0, aY1, aX0, aX1)
        PLANE( 2,  1, aX0, aX1, aZ0, aZ1, aY0, aY1)
        PLANE( 3,  2, aY0, aY1, aX0, aX1, aZ0, aZ1)
        PLANE( 4,  3, aZ0, aZ1, aY0, aY1, aX0, aX1)
        PLANE( 5,  4, aX0, aX1, aZ0, aZ1, aY0, aY1)
        PLANE( 6,  5, aY0, aY1, aX0, aX1, aZ0, aZ1)
        PLANE( 7,  6, aZ0, aZ1, aY0, aY1, aX0, aX1)
        PLANE( 8,  7, aX0, aX1, aZ0, aZ1, aY0, aY1)
        PLANE( 9,  8, aY0, aY1, aX0, aX1, aZ0, aZ1)
        PLANE(10,  9, aZ0, aZ1, aY0, aY1, aX0, aX1)
        PLANE(11, 10, aX0, aX1, aZ0, aZ1, aY0, aY1)
        PLANE(12, 11, aY0, aY1, aX0, aX1, aZ0, aZ1)
        PLANE(13, 12, aZ0, aZ1, aY0, aY1, aX0, aX1)
        PLANE(14, 13, aX0, aX1, aZ0, aZ1, aY0, aY1)
        PLANE(15, 14, aY0, aY1, aX0, aX1, aZ0, aZ1)
        PLANE(16, 15, aZ0, aZ1, aY0, aY1, aX0, aX1)
        PLANE(17, 16, aX0, aX1, aZ0, aZ1, aY0, aY1)
        PLANE(18, 17, aY0, aY1, aX0, aX1, aZ0, aZ1)
        PLANE(19, 18, aZ0, aZ1, aY0, aY1, aX0, aX1)
        PLANE(20, 19, aX0, aX1, aZ0, aZ1, aY0, aY1)
        PLANE(21, 20, aY0, aY1, aX0, aX1, aZ0, aZ1)
        PLANE(22, 21, aZ0, aZ1, aY0, aY1, aX0, aX1)
        PLANE(23, 22, aX0, aX1, aZ0, aZ1, aY0, aY1)
        PLANE(24, 23, aY0, aY1, aX0, aX1, aZ0, aZ1)
        PLANE(25, 24, aZ0, aZ1, aY0, aY1, aX0, aX1)
        PLANE(26, 25, aX0, aX1, aZ0, aZ1, aY0, aY1)
        PLANE(27, 26, aY0, aY1, aX0, aX1, aZ0, aZ1)
        PLANE(28, 27, aZ0, aZ1, aY0, aY1, aX0, aX1)
        PLANE(29, 28, aX0, aX1, aZ0, aZ1, aY0, aY1)
        PLANE(30, 29, aY0, aY1, aX0, aX1, aZ0, aZ1)
        PLANE(31, 30, aZ0, aZ1, aY0, aY1, aX0, aX1)
        { // finalize output plane 31 (slot Y: plane30 kd=0 + plane31 kd=1)
            const float pre0 = aY0 + nb_31.x;
            const float pre1 = aY1 + nb_31.y;
            const float h0 = 1.0f - 2.0f * __builtin_amdgcn_rcpf(
                __builtin_amdgcn_exp2f(pre0 * 2.8853900817779268f) + 1.0f);
            const float h1 = 1.0f - 2.0f * __builtin_amdgcn_rcpf(
                __builtin_amdgcn_exp2f(pre1 * 2.8853900817779268f) + 1.0f);
            __syncthreads();   // all reads of S[31] (PLANE 31) done before overwrite
            S[31][ty + 1][tx2 + 1] = 0.5f * (c0 + h0);
            S[31][ty + 1][tx2 + 2] = 0.5f * (c1 + h1);
        }
    }
    __syncthreads();   // state complete & visible

    // ---- fused output GEMM: out[b][o] = sum_flat s * W_out[o][flat] + b_out[o]
    float p0 = 0.f, p1 = 0.f, p2 = 0.f, p3 = 0.f, p4 = 0.f;
    float p5 = 0.f, p6 = 0.f, p7 = 0.f, p8 = 0.f, p9 = 0.f;
    const int base = tid * 4;
#pragma unroll 4
    for (int j = 0; j < 16; ++j) {
        const int idx = base + j * 2048;
        const int d   = idx >> 10;
        const int rem = idx & 1023;
        const int yy  = rem >> 5;
        const int xx  = rem & 31;
        const float s0v = S[d][yy + 1][xx + 1];
        const float s1v = S[d][yy + 1][xx + 2];
        const float s2v = S[d][yy + 1][xx + 3];
        const float s3v = S[d][yy + 1][xx + 4];
#define OACC(o) { const float4 wv = *(const float4*)&W_out[(size_t)(o) * 32768 + idx]; \
        p##o = fmaf(s0v, wv.x, p##o); p##o = fmaf(s1v, wv.y, p##o);            \
        p##o = fmaf(s2v, wv.z, p##o); p##o = fmaf(s3v, wv.w, p##o); }
        OACC(0) OACC(1) OACC(2) OACC(3) OACC(4)
        OACC(5) OACC(6) OACC(7) OACC(8) OACC(9)
#undef OACC
    }

    const int lane = tid & 63, wvi = tid >> 6;
#define RED(o) { float t = p##o;                                               \
    t += __shfl_down(t, 32, 64); t += __shfl_down(t, 16, 64);                  \
    t += __shfl_down(t, 8, 64);  t += __shfl_down(t, 4, 64);                   \
    t += __shfl_down(t, 2, 64);  t += __shfl_down(t, 1, 64);                   \
    if (lane == 0) red[o][wvi] = t; }
    RED(0) RED(1) RED(2) RED(3) RED(4) RED(5) RED(6) RED(7) RED(8) RED(9)
#undef RED
    __syncthreads();
    if (tid < 10) {
        float sum = b_out[tid];
#pragma unroll
        for (int w8 = 0; w8 < 8; ++w8) sum += red[tid][w8];
        out[(size_t)b * 10 + tid] = sum;
    }
}

// ---------------- launcher ----------------
extern "C" void kernel_launch(void* const* d_in, const int* in_sizes, int n_in,
                              void* d_out, int out_size, void* d_ws, size_t ws_size,
                              hipStream_t stream) {
    const float* x      = (const float*)d_in[0];
    const float* W_in   = (const float*)d_in[1];
    const float* b_in   = (const float*)d_in[2];
    const float* conv_w = (const float*)d_in[3];
    const float* nbias  = (const float*)d_in[4];
    const float* W_out  = (const float*)d_in[5];
    const float* b_out  = (const float*)d_in[6];
    const int*   steps  = (const int*)d_in[7];
    float* out = (float*)d_out;
    float* surface = (float*)d_ws;   // 1024*1024 f32 = 4 MB scratch

    in_gemm<<<dim3(16, 16), 256, 0, stream>>>(x, W_in, b_in, surface);
    cube_evolve<<<1024, dim3(16, 32), 0, stream>>>(surface, conv_w, nbias,
                                                   W_out, b_out, steps, out);
}